// Round 9
// baseline (496.603 us; speedup 1.0000x reference)
//
#include <hip/hip_runtime.h>
#include <hip/hip_bf16.h>
#include <cstdint>
#include <cstddef>

// Problem constants
#define BATCH 8
#define SEQN 4096
#define DIM 1024
#define KSLOT 128
#define MROWS (BATCH * SEQN)   // 32768
#define LN_EPS 1e-5f

typedef __hip_bfloat16 bf16;
typedef __attribute__((ext_vector_type(8))) short short8;   // 8 bf16 = 4 VGPRs (MFMA A/B frag)
typedef __attribute__((ext_vector_type(4))) float f32x4;    // MFMA C/D frag

// ---------- helpers ----------
__device__ __forceinline__ float bf2f(unsigned short u) {
    return __uint_as_float(((unsigned int)u) << 16);
}
__device__ __forceinline__ unsigned short f2bf(float f) {
    unsigned int u = __float_as_uint(f);
    unsigned int r = (u + 0x7fffu + ((u >> 16) & 1u)) >> 16;  // RNE
    return (unsigned short)r;
}
__device__ __forceinline__ float waveReduceSum(float v) {
    #pragma unroll
    for (int off = 32; off > 0; off >>= 1) v += __shfl_down(v, off, 64);
    return v;
}
__device__ __forceinline__ void load4(const float* p, float* o) {
    float4 v = *reinterpret_cast<const float4*>(p);
    o[0] = v.x; o[1] = v.y; o[2] = v.z; o[3] = v.w;
}
__device__ __forceinline__ void store4(float* p, const float* o) {
    float4 v; v.x = o[0]; v.y = o[1]; v.z = o[2]; v.w = o[3];
    *reinterpret_cast<float4*>(p) = v;
}

// async global->LDS, 16 B per lane (global_load_lds_dwordx4)
typedef __attribute__((address_space(1))) const void gvoid;
typedef __attribute__((address_space(3))) void lvoid;
__device__ __forceinline__ void async_cp16(const void* g, void* l) {
    __builtin_amdgcn_global_load_lds((gvoid*)g, (lvoid*)l, 16, 0, 0);
}

// ---------- fp32 SIMT NN GEMM partial (split-K over blockIdx.z=8) ----------
// P[z,k,d] = sum_{e in chunk z} A[k,e] * B[e,d]
__global__ __launch_bounds__(256) void nn_partial(
    const float* __restrict__ A, const float* __restrict__ B,
    float* __restrict__ P, int Ka, int E, int Db)
{
    __shared__ float As[16][68];
    __shared__ float Bs[16][68];
    int tid = threadIdx.x, tx = tid & 15, ty = tid >> 4;
    int k0 = blockIdx.x * 64, d0 = blockIdx.y * 64;
    int chunk = E >> 3, e0 = blockIdx.z * chunk;
    int lr = tid >> 2, lk = (tid & 3) * 4;     // A staging: row k0+lr, e off lk
    int er = tid >> 4, dc = (tid & 15) * 4;    // B staging: row e0+et+er, col d0+dc
    float acc[4][4] = {};
    for (int et = 0; et < chunk; et += 16) {
        float av[4], bv[4];
        load4(A + (size_t)(k0 + lr) * E + e0 + et + lk, av);
        load4(B + (size_t)(e0 + et + er) * Db + d0 + dc, bv);
        #pragma unroll
        for (int j = 0; j < 4; j++) { As[lk + j][lr] = av[j]; Bs[er][dc + j] = bv[j]; }
        __syncthreads();
        #pragma unroll
        for (int kk = 0; kk < 16; kk++) {
            float a_[4], b_[4];
            #pragma unroll
            for (int i = 0; i < 4; i++) { a_[i] = As[kk][ty * 4 + i]; b_[i] = Bs[kk][tx * 4 + i]; }
            #pragma unroll
            for (int i = 0; i < 4; i++)
                #pragma unroll
                for (int j = 0; j < 4; j++) acc[i][j] += a_[i] * b_[j];
        }
        __syncthreads();
    }
    float* base = P + ((size_t)blockIdx.z * Ka + k0) * Db + d0;
    #pragma unroll
    for (int i = 0; i < 4; i++) store4(base + (size_t)(ty * 4 + i) * Db + tx * 4, acc[i]);
}

// ---------- w1 prep: wc = sum_z P1; wg = wc * ln_g; split hi/lo; u = sum_d wg; v = sum_d wc*ln_b ----------
__global__ __launch_bounds__(256) void w1_prep(
    const float* __restrict__ P1, const float* __restrict__ g, const float* __restrict__ lb,
    bf16* __restrict__ hi, bf16* __restrict__ lo,
    float* __restrict__ u, float* __restrict__ v)
{
    int k = blockIdx.x, tid = threadIdx.x;
    int d = tid * 4;
    float wcf[4] = {0.f, 0.f, 0.f, 0.f};
    #pragma unroll
    for (int z = 0; z < 8; z++) {
        float t[4];
        load4(P1 + ((size_t)z * KSLOT + k) * DIM + d, t);
        #pragma unroll
        for (int j = 0; j < 4; j++) wcf[j] += t[j];
    }
    float gv[4], bv[4];
    load4(g + d, gv);
    load4(lb + d, bv);
    float su = 0.f, sv = 0.f;
    ushort4 h, l;
    unsigned short hb[4], lbv[4];
    #pragma unroll
    for (int j = 0; j < 4; j++) {
        float wg = wcf[j] * gv[j];
        hb[j] = f2bf(wg);
        lbv[j] = f2bf(wg - bf2f(hb[j]));
        su += wg;
        sv += wcf[j] * bv[j];
    }
    h.x = hb[0]; h.y = hb[1]; h.z = hb[2]; h.w = hb[3];
    l.x = lbv[0]; l.y = lbv[1]; l.z = lbv[2]; l.w = lbv[3];
    reinterpret_cast<ushort4*>(hi)[((size_t)k * DIM + d) >> 2] = h;
    reinterpret_cast<ushort4*>(lo)[((size_t)k * DIM + d) >> 2] = l;
    su = waveReduceSum(su);
    sv = waveReduceSum(sv);
    __shared__ float sU[4], sV[4];
    int w = tid >> 6;
    if ((tid & 63) == 0) { sU[w] = su; sV[w] = sv; }
    __syncthreads();
    if (tid == 0) {
        u[k] = sU[0] + sU[1] + sU[2] + sU[3];
        v[k] = sV[0] + sV[1] + sV[2] + sV[3];
    }
}

// ---------- w2 split: reduce 8 partials of P2 -> hi/lo bf16 ----------
__global__ __launch_bounds__(256) void w2_split(
    const float* __restrict__ P, bf16* __restrict__ hi, bf16* __restrict__ lo, int n)
{
    int i = (blockIdx.x * 256 + threadIdx.x) * 4;
    if (i >= n) return;
    float s[4] = {0.f, 0.f, 0.f, 0.f};
    #pragma unroll
    for (int z = 0; z < 8; z++) {
        float t[4];
        load4(P + (size_t)z * n + i, t);
        #pragma unroll
        for (int j = 0; j < 4; j++) s[j] += t[j];
    }
    ushort4 h, l;
    unsigned short hb[4], lb[4];
    #pragma unroll
    for (int j = 0; j < 4; j++) {
        hb[j] = f2bf(s[j]);
        lb[j] = f2bf(s[j] - bf2f(hb[j]));
    }
    h.x = hb[0]; h.y = hb[1]; h.z = hb[2]; h.w = hb[3];
    l.x = lb[0]; l.y = lb[1]; l.z = lb[2]; l.w = lb[3];
    reinterpret_cast<ushort4*>(hi)[i >> 2] = h;
    reinterpret_cast<ushort4*>(lo)[i >> 2] = l;
}

// ---------- bias0[k] = sum_e w0[k,e] * b_in[e] ----------
__global__ __launch_bounds__(64) void bias_comb(
    const float* __restrict__ w0, const float* __restrict__ b_in, float* __restrict__ bias0)
{
    int k = blockIdx.x, lane = threadIdx.x;
    float s = 0.0f;
    for (int e = lane; e < DIM; e += 64) s += w0[(size_t)k * DIM + e] * b_in[e];
    s = waveReduceSum(s);
    if (lane == 0) bias0[k] = s;
}

// ---------- fused LN + logits GEMM, 32-row tiles ----------
// logits[m,k] = rstd_m * (x_bf16 @ wg^T)[m,k] - rstd_m*mean_m*u[k] + v[k] + bias0[k]
// 1024 blocks x 256 thr (4 waves), ~18 KB LDS, low VGPR -> target ~8 blocks/CU so
// block-level TLP hides the per-kt vmcnt(0)+barrier drain (x HBM latency).
__global__ __launch_bounds__(256) void gemm_logits_fused(
    const float* __restrict__ x, const bf16* __restrict__ Whi, const bf16* __restrict__ Wlo,
    const float* __restrict__ u, const float* __restrict__ v, const float* __restrict__ bias0,
    float* __restrict__ C)
{
    __shared__ short Wh[128 * 32];   // 8 KB
    __shared__ short Wl[128 * 32];   // 8 KB
    __shared__ short As[32 * 32];    // 2 KB
    __shared__ float rowM[32], rowR[32];
    const int tid = threadIdx.x, wave = tid >> 6, lane = tid & 63;
    const int wm = wave >> 1, wn = wave & 1;           // wave: 16 rows x 64 cols
    const int m0 = blockIdx.x * 32;
    const int srow = tid >> 2, scol = (tid & 3) * 8;   // W staging: 64 rows x 32 k
    const bf16* hG0 = Whi + (size_t)srow * DIM + scol;
    const bf16* hG1 = hG0 + (size_t)64 * DIM;
    const bf16* lG0 = Wlo + (size_t)srow * DIM + scol;
    const bf16* lG1 = lG0 + (size_t)64 * DIM;
    short* hL0 = Wh + tid * 8;  short* hL1 = Wh + 2048 + tid * 8;
    short* lL0 = Wl + tid * 8;  short* lL1 = Wl + 2048 + tid * 8;
    const int xrow = tid >> 3, xcol = (tid & 7) * 4;   // x staging: 32 rows x 32 k fp32
    const float* xG = x + (size_t)(m0 + xrow) * DIM + xcol;
    const int fr = lane & 15, kb = (lane >> 4) * 8;

    f32x4 acc[4];
    #pragma unroll
    for (int j = 0; j < 4; j++) acc[j] = 0.0f;

    float s_acc = 0.0f, q_acc = 0.0f;

    for (int kt = 0; kt < DIM; kt += 32) {
        async_cp16(hG0 + kt, hL0);
        async_cp16(hG1 + kt, hL1);
        async_cp16(lG0 + kt, lL0);
        async_cp16(lG1 + kt, lL1);
        // A-staging: raw x fp32 -> bf16, accumulate row stats
        float xv[4];
        load4(xG + kt, xv);
        ushort4 pk;
        unsigned short pb[4];
        #pragma unroll
        for (int j = 0; j < 4; j++) {
            pb[j] = f2bf(xv[j]);
            s_acc += xv[j];
            q_acc += xv[j] * xv[j];
        }
        pk.x = pb[0]; pk.y = pb[1]; pk.z = pb[2]; pk.w = pb[3];
        *(ushort4*)(As + xrow * 32 + xcol) = pk;
        __syncthreads();
        short8 af, bh[4], bl[4];
        af = *(const short8*)(As + (wm * 16 + fr) * 32 + kb);
        #pragma unroll
        for (int j = 0; j < 4; j++) {
            bh[j] = *(const short8*)(Wh + (wn * 64 + j * 16 + fr) * 32 + kb);
            bl[j] = *(const short8*)(Wl + (wn * 64 + j * 16 + fr) * 32 + kb);
        }
        #pragma unroll
        for (int j = 0; j < 4; j++) {
            acc[j] = __builtin_amdgcn_mfma_f32_16x16x32_bf16(af, bh[j], acc[j], 0, 0, 0);
            acc[j] = __builtin_amdgcn_mfma_f32_16x16x32_bf16(af, bl[j], acc[j], 0, 0, 0);
        }
        __syncthreads();
    }

    // row stats: 8 threads per row (consecutive lanes), xor-reduce within 8
    s_acc += __shfl_xor(s_acc, 1, 64);  q_acc += __shfl_xor(q_acc, 1, 64);
    s_acc += __shfl_xor(s_acc, 2, 64);  q_acc += __shfl_xor(q_acc, 2, 64);
    s_acc += __shfl_xor(s_acc, 4, 64);  q_acc += __shfl_xor(q_acc, 4, 64);
    if ((tid & 7) == 0) {
        float mean = s_acc * (1.0f / DIM);
        float var  = q_acc * (1.0f / DIM) - mean * mean;
        rowM[xrow] = mean;
        rowR[xrow] = rsqrtf(fmaxf(var, 0.0f) + LN_EPS);
    }
    __syncthreads();

    const int crow = (lane >> 4) * 4;   // C/D: col=lane&15, row=(lane>>4)*4+reg
    #pragma unroll
    for (int j = 0; j < 4; j++) {
        int col = wn * 64 + j * 16 + fr;
        float uc = u[col];
        float vc = v[col] + bias0[col];
        #pragma unroll
        for (int r = 0; r < 4; r++) {
            int rl = wm * 16 + crow + r;
            float rstd = rowR[rl], mean = rowM[rl];
            C[(size_t)(m0 + rl) * KSLOT + col] = rstd * acc[j][r] - rstd * mean * uc + vc;
        }
    }
}

// ---------- softmax over N: coalesced partial stats (float4 row-major reads) ----------
__global__ __launch_bounds__(256) void smax_part_c(
    const float* __restrict__ logits, float* __restrict__ pm, float* __restrict__ ps)
{
    int nb = blockIdx.x, b = blockIdx.y;
    int t = threadIdx.x;
    int kq = (t & 31) * 4, rg = t >> 5;          // 4 k-cols, row-group 0..7
    const float* base = logits + ((size_t)(b * SEQN + nb * 256 + rg)) * KSLOT + kq;
    float m[4] = {-1e30f, -1e30f, -1e30f, -1e30f};
    float s[4] = {0.f, 0.f, 0.f, 0.f};
    for (int it = 0; it < 32; it++) {
        float vv[4];
        load4(base + (size_t)it * 8 * KSLOT, vv);
        #pragma unroll
        for (int j = 0; j < 4; j++) {
            float vj = vv[j];
            if (vj > m[j]) { s[j] = s[j] * __expf(m[j] - vj) + 1.0f; m[j] = vj; }
            else           { s[j] += __expf(vj - m[j]); }
        }
    }
    __shared__ float lm[8][128], ls[8][128];     // 8 KB
    #pragma unroll
    for (int j = 0; j < 4; j++) { lm[rg][kq + j] = m[j]; ls[rg][kq + j] = s[j]; }
    __syncthreads();
    if (t < 128) {
        float M = -1e30f, S = 0.f;
        #pragma unroll
        for (int r2 = 0; r2 < 8; r2++) {
            float m2 = lm[r2][t], s2 = ls[r2][t];
            float nm = fmaxf(M, m2);
            S = S * __expf(M - nm) + s2 * __expf(m2 - nm);
            M = nm;
        }
        int col = b * KSLOT + t;
        pm[col * 16 + nb] = M;
        ps[col * 16 + nb] = S;
    }
}

__global__ __launch_bounds__(256) void smax_comb_kernel(
    const float* __restrict__ pm, const float* __restrict__ ps,
    float* __restrict__ cm, float* __restrict__ cs)
{
    int c = blockIdx.x * 256 + threadIdx.x;  // 0..1023 = b*K+k
    float m = -1e30f, s = 0.0f;
    #pragma unroll
    for (int nb = 0; nb < 16; nb++) {
        float m2 = pm[c * 16 + nb], s2 = ps[c * 16 + nb];
        float nm = fmaxf(m, m2);
        s = s * __expf(m - nm) + s2 * __expf(m2 - nm);
        m = nm;
    }
    cm[c] = m;
    cs[c] = s;
}

// ---------- fused tail: l1-norm -> h3 GEMM (16-row strip, full D) -> LN -> relu(+x) ----------
// 2048 blocks x 256 thr (4 waves), __launch_bounds__(256,4) -> 4 blocks/CU so block-level
// TLP overlaps phase-2 (L2/MFMA) of one block with phase-4 (HBM) of another.
// Swapped MFMA operands (w-frag first): acc[j] holds
//   d = cbase + j*16 + gq*4 + r  (4 consecutive d per lane), m = fr.
// Epilogue: compute relu(...) INTO acc in place, then stores in j-pairs back-to-back so
// each 128-B out line is completed by two adjacent 64-B stores (kills round-5's write-amp).
__global__ __launch_bounds__(256, 4) void h3_fused(
    const float* __restrict__ logits, const float* __restrict__ cm, const float* __restrict__ cs,
    const bf16* __restrict__ Whi, const bf16* __restrict__ Wlo,
    const float* __restrict__ x, const float* __restrict__ g, const float* __restrict__ bb,
    float* __restrict__ out)
{
    __shared__ short As[16 * 128];          // 4 KB, XOR-swizzled a-tile (bf16)
    __shared__ float redS[4][16];           // per-wave row partial sums
    __shared__ float redQ[4][16];
    __shared__ float mrowM[16], mrowR[16];  // per-row mean / rstd

    const int tid  = threadIdx.x;
    const int wave = tid >> 6, lane = tid & 63;
    const int fr = lane & 15, gq = lane >> 4;        // gq in 0..3
    const int r0 = blockIdx.x * 16;
    const int bIdx = r0 >> 12;                        // batch index (SEQN=4096)

    // ---- phase 1: a[row,k] = softmax/L1 of logits -> LDS bf16 (swizzled) ----
    {
        int row = tid >> 4;               // 0..15
        int c0  = (tid & 15) * 8;         // 0..120
        const float* lp = logits + (size_t)(r0 + row) * KSLOT + c0;
        float v[8], cmv[8], csv[8];
        load4(lp, v);                 load4(lp + 4, v + 4);
        const float* cmp = cm + bIdx * KSLOT + c0;
        const float* csp = cs + bIdx * KSLOT + c0;
        load4(cmp, cmv);              load4(cmp + 4, cmv + 4);
        load4(csp, csv);              load4(csp + 4, csv + 4);
        float e[8], s = 0.0f;
        #pragma unroll
        for (int j = 0; j < 8; j++) { e[j] = __expf(v[j] - cmv[j]) / csv[j]; s += e[j]; }
        #pragma unroll
        for (int off = 1; off < 16; off <<= 1) s += __shfl_xor(s, off, 64);  // 16 lanes = 1 row
        float inv = 1.0f / (1e-9f + s);
        short8 pk;
        #pragma unroll
        for (int j = 0; j < 8; j++) pk[j] = (short)f2bf(e[j] * inv);
        int csw = c0 ^ ((row & 7) << 3);  // 16B-granular XOR swizzle
        *(short8*)(As + row * 128 + csw) = pk;
    }
    __syncthreads();

    // ---- phase 2: h3[16 x 256(wave)] = a @ (Whi+Wlo)^T, B from global (L2-hot) ----
    const int cbase = wave * 256;
    const int kb = gq * 8;
    f32x4 acc[16];
    #pragma unroll
    for (int j = 0; j < 16; j++) acc[j] = 0.0f;

    for (int kt = 0; kt < KSLOT; kt += 32) {
        short8 af = *(const short8*)(As + fr * 128 + ((kt + kb) ^ ((fr & 7) << 3)));
        #pragma unroll
        for (int j = 0; j < 16; j++) {
            int d = cbase + j * 16 + fr;
            short8 bh = *(const short8*)((const short*)Whi + (size_t)d * KSLOT + kt + kb);
            short8 bl = *(const short8*)((const short*)Wlo + (size_t)d * KSLOT + kt + kb);
            // swapped operands: w-frag first -> d indexes C/D "row" (gq*4+r)
            acc[j] = __builtin_amdgcn_mfma_f32_16x16x32_bf16(bh, af, acc[j], 0, 0, 0);
            acc[j] = __builtin_amdgcn_mfma_f32_16x16x32_bf16(bl, af, acc[j], 0, 0, 0);
        }
    }

    // ---- phase 3: per-row LN stats (h3 stays in fp32 regs) ----
    // acc[j][r]: m = fr, d = cbase + j*16 + gq*4 + r
    {
        float s = 0.0f, q = 0.0f;
        #pragma unroll
        for (int j = 0; j < 16; j++)
            #pragma unroll
            for (int r = 0; r < 4; r++) {
                float v = acc[j][r];
                s += v; q += v * v;
            }
        // reduce across gq (lanes ^16, ^32 share the same m-row fr)
        s += __shfl_xor(s, 16, 64);  q += __shfl_xor(q, 16, 64);
        s += __shfl_xor(s, 32, 64);  q += __shfl_xor(q, 32, 64);
        if (gq == 0) { redS[wave][fr] = s; redQ[wave][fr] = q; }
    }
    __syncthreads();
    if (tid < 16) {
        float S = 0.0f, Q = 0.0f;
        #pragma unroll
        for (int w = 0; w < 4; w++) { S += redS[w][tid]; Q += redQ[w][tid]; }
        float mean = S * (1.0f / DIM);
        float var  = Q * (1.0f / DIM) - mean * mean;
        mrowM[tid] = mean;
        mrowR[tid] = rsqrtf(fmaxf(var, 0.0f) + LN_EPS);
    }
    __syncthreads();

    // ---- phase 4: out = relu(LN(h3)*g + b + x) computed IN PLACE, paired stores ----
    {
        float mean = mrowM[fr], rstd = mrowR[fr];
        const float* xr = x   + (size_t)(r0 + fr) * DIM;
        float*       orow = out + (size_t)(r0 + fr) * DIM;
        #pragma unroll
        for (int jp = 0; jp < 8; jp++) {
            int j0 = jp * 2;
            int d0 = cbase + j0 * 16 + gq * 4;
            int d1 = d0 + 16;
            float gv0[4], bv0[4], xv0[4], gv1[4], bv1[4], xv1[4];
            load4(g + d0, gv0);  load4(bb + d0, bv0);  load4(xr + d0, xv0);
            load4(g + d1, gv1);  load4(bb + d1, bv1);  load4(xr + d1, xv1);
            #pragma unroll
            for (int r = 0; r < 4; r++) {
                acc[j0][r]     = fmaxf((acc[j0][r]     - mean) * rstd * gv0[r] + bv0[r] + xv0[r], 0.0f);
                acc[j0 + 1][r] = fmaxf((acc[j0 + 1][r] - mean) * rstd * gv1[r] + bv1[r] + xv1[r], 0.0f);
            }
            // back-to-back 64-B stores complete each 128-B line (cols 32-aligned pair)
            *reinterpret_cast<f32x4*>(orow + d0) = acc[j0];
            *reinterpret_cast<f32x4*>(orow + d1) = acc[j0 + 1];
        }
    }
}

extern "C" void kernel_launch(void* const* d_in, const int* in_sizes, int n_in,
                              void* d_out, int out_size, void* d_ws, size_t ws_size,
                              hipStream_t stream)
{
    const float* x     = (const float*)d_in[0];
    const float* ln_g  = (const float*)d_in[1];
    const float* ln_b  = (const float*)d_in[2];
    const float* w_in  = (const float*)d_in[3];
    const float* b_in  = (const float*)d_in[4];
    const float* w0    = (const float*)d_in[5];
    const float* w1    = (const float*)d_in[6];
    const float* w_out = (const float*)d_in[7];
    const float* oln_g = (const float*)d_in[8];
    const float* oln_b = (const float*)d_in[9];
    float* out = (float*)d_out;   // final fp32 output only

    // ws layout:
    //   [64, 80 MiB)  P1 [64,68) + P2 [68,72) (dead after w1_prep/w2_split), then logits fp32
    //   [80 MiB, ..)  wc_hi/wc_lo/wc2_hi/wc2_lo/bias0/softmax stats/u/v
    char* ws = (char*)d_ws;
    float* logits = (float*)(ws + 67108864);
    float* P1     = (float*)(ws + 67108864);            // 8x128x1024 fp32 = 4 MiB
    float* P2     = (float*)(ws + 71303168);            // 8x1024x128 fp32 = 4 MiB
    bf16*  wc_hi  = (bf16*)(ws + 83886080);             // 128x1024 (g folded in)
    bf16*  wc_lo  = (bf16*)(ws + 84148224);
    bf16*  wc2_hi = (bf16*)(ws + 84410368);             // 1024x128
    bf16*  wc2_lo = (bf16*)(ws + 84672512);
    float* bias0  = (float*)(ws + 84934656);            // 128 f
    float* pm     = (float*)(ws + 84935168);            // 16384 f
    float* psum   = (float*)(ws + 85000704);            // 16384 f
    float* cm     = (float*)(ws + 85066240);            // 1024 f
    float* cs     = (float*)(ws + 85070336);            // 1024 f
    float* uvec   = (float*)(ws + 85074432);            // 128 f
    float* vvec   = (float*)(ws + 85078528);            // 128 f

    // 0a. w_comb partials = w0 @ w_in  (128x1024), split-K 8
    nn_partial<<<dim3(2, 16, 8), dim3(256), 0, stream>>>(w0, w_in, P1, KSLOT, DIM, DIM);
    // 0b. w_comb2 partials = w_out @ w1 (1024x128), split-K 8
    nn_partial<<<dim3(16, 2, 8), dim3(256), 0, stream>>>(w_out, w1, P2, DIM, DIM, KSLOT);
    // 0c. bias0 = w0 @ b_in
    bias_comb<<<dim3(KSLOT), dim3(64), 0, stream>>>(w0, b_in, bias0);
    // 0d. w1: reduce + fold ln_g + hi/lo split + u,v vectors (LN folded into GEMM epilogue)
    w1_prep<<<dim3(KSLOT), dim3(256), 0, stream>>>(P1, ln_g, ln_b, wc_hi, wc_lo, uvec, vvec);
    // 0e. w2: reduce + hi/lo split
    w2_split<<<dim3(128), dim3(256), 0, stream>>>(P2, wc2_hi, wc2_lo, KSLOT * DIM);
    // 1+2. logits = LN(x) @ wc^T + bias0, LN folded; 32-row tiles -> ~8 blocks/CU
    gemm_logits_fused<<<dim3(MROWS / 32), dim3(256), 0, stream>>>(
        x, wc_hi, wc_lo, uvec, vvec, bias0, logits);
    // 3-4. column softmax stats over N (coalesced float4 reads)
    smax_part_c<<<dim3(16, BATCH), dim3(256), 0, stream>>>(logits, pm, psum);
    smax_comb_kernel<<<dim3(4), dim3(256), 0, stream>>>(pm, psum, cm, cs);
    // 5-7. fused tail; 16-row strips -> 4 blocks/CU for cross-block phase overlap
    h3_fused<<<dim3(MROWS / 16), dim3(256), 0, stream>>>(
        logits, cm, cs, wc2_hi, wc2_lo, x, oln_g, oln_b, out);
}